// Round 1
// 445.328 us; speedup vs baseline: 1.1015x; 1.1015x over previous
//
#include <hip/hip_runtime.h>
#include <hip/hip_fp16.h>

#define N_NODES 100000
#define N_EDGES 1200000
#define TOTAL_E (2 * N_EDGES)
#define D 64

#define BSH 7                       // bucket = node >> 7 (128 nodes/bucket)
#define NBUCK 782                   // ceil(100000/128)
#define NCHUNK 320
#define CHUNK 7500                  // NCHUNK * CHUNK == TOTAL_E
#define HIST_L (NBUCK * NCHUNK)     // 250240 (per side; hist array holds 2x)
#define SCAN_BS 256
#define SCAN_NB ((HIST_L + SCAN_BS - 1) / SCAN_BS)  // 978
#define ENT_CAP 4608                // bucket mean 3072, sigma 55 -> +28 sigma

// ---------------------------------------------------------------------------
// Per-chunk LDS histograms of dst buckets AND src buckets. No global atomics
// (the old per-edge cntO atomicAdds wrote ~77 MB through to HBM and bounded
// this kernel at ~0.85 TB/s scattered-write throughput).
// hist layout: [0, HIST_L) = dst-side, [HIST_L, 2*HIST_L) = src-side.
// ---------------------------------------------------------------------------
__global__ __launch_bounds__(512) void countA_kernel(const int* __restrict__ s0,
                                                     const int* __restrict__ d0,
                                                     const int* __restrict__ s1,
                                                     const int* __restrict__ d1,
                                                     int* __restrict__ hist) {
    __shared__ int hD[NBUCK];
    __shared__ int hS[NBUCK];
    int t = threadIdx.x;
    for (int i = t; i < NBUCK; i += 512) { hD[i] = 0; hS[i] = 0; }
    __syncthreads();
    int base = blockIdx.x * CHUNK;
    for (int i = t; i < CHUNK; i += 512) {
        int e = base + i;
        int rel = (e >= N_EDGES);
        int src = rel ? s1[e - N_EDGES] : s0[e];
        int dst = rel ? d1[e - N_EDGES] : d0[e];
        atomicAdd(&hD[dst >> BSH], 1);
        atomicAdd(&hS[src >> BSH], 1);
    }
    __syncthreads();
    for (int i = t; i < NBUCK; i += 512) {
        hist[i * NCHUNK + blockIdx.x] = hD[i];
        hist[HIST_L + i * NCHUNK + blockIdx.x] = hS[i];
    }
}

// ---------------------------------------------------------------------------
// Exclusive scan over HIST_L ints (invoked twice: dst half, src half).
// ---------------------------------------------------------------------------
__global__ void scan1_kernel(const int* __restrict__ in, int* __restrict__ out,
                             int* __restrict__ bsum) {
    __shared__ int s[SCAN_BS];
    int t = threadIdx.x;
    int i = blockIdx.x * SCAN_BS + t;
    int v = (i < HIST_L) ? in[i] : 0;
    s[t] = v;
    __syncthreads();
    for (int off = 1; off < SCAN_BS; off <<= 1) {
        int add = (t >= off) ? s[t - off] : 0;
        __syncthreads();
        s[t] += add;
        __syncthreads();
    }
    if (i < HIST_L) out[i] = s[t] - v;
    if (t == SCAN_BS - 1) bsum[blockIdx.x] = s[t];
}

__global__ void scan2_kernel(int* __restrict__ bsum) {
    __shared__ int s[1024];
    int t = threadIdx.x;
    int v = (t < SCAN_NB) ? bsum[t] : 0;
    s[t] = v;
    __syncthreads();
    for (int off = 1; off < 1024; off <<= 1) {
        int add = (t >= off) ? s[t - off] : 0;
        __syncthreads();
        s[t] += add;
        __syncthreads();
    }
    if (t < SCAN_NB) bsum[t] = s[t] - v;
}

__global__ void scan3_kernel(int* __restrict__ out, const int* __restrict__ bsum) {
    int i = blockIdx.x * SCAN_BS + threadIdx.x;
    if (i < HIST_L) out[i] += bsum[blockIdx.x];
    if (i == 0) out[HIST_L] = TOTAL_E;
}

// ---------------------------------------------------------------------------
// Scatter packed entries into bucket-binned arrays.
// dst entry (u32) = src | dl<<17 | rel<<24  -> binned
// src entry (u8)  = sl | rel<<7             -> binnedS (for out-degree counts)
// ---------------------------------------------------------------------------
__global__ __launch_bounds__(512) void scatterA_kernel(const int* __restrict__ s0,
                                                       const int* __restrict__ d0,
                                                       const int* __restrict__ s1,
                                                       const int* __restrict__ d1,
                                                       const int* __restrict__ ofs,
                                                       const int* __restrict__ ofsS,
                                                       unsigned* __restrict__ binned,
                                                       unsigned char* __restrict__ binnedS) {
    __shared__ int cur[NBUCK];
    __shared__ int curS[NBUCK];
    int t = threadIdx.x, wg = blockIdx.x;
    for (int b = t; b < NBUCK; b += 512) {
        cur[b] = ofs[b * NCHUNK + wg];
        curS[b] = ofsS[b * NCHUNK + wg];
    }
    __syncthreads();
    int base = wg * CHUNK;
    for (int i = t; i < CHUNK; i += 512) {
        int e = base + i;
        int rel = (e >= N_EDGES);
        int src = rel ? s1[e - N_EDGES] : s0[e];
        int dst = rel ? d1[e - N_EDGES] : d0[e];
        int p = atomicAdd(&cur[dst >> BSH], 1);
        binned[p] = (unsigned)src | ((unsigned)(dst & 127) << 17) | ((unsigned)rel << 24);
        int q = atomicAdd(&curS[src >> BSH], 1);
        binnedS[q] = (unsigned char)((src & 127) | (rel << 7));
    }
}

// ---------------------------------------------------------------------------
// Per-bucket LDS counting sort (in place): binned -> src indices grouped by
// key = dl | rel<<7; per-(node,rel) offsets/counts.
// ---------------------------------------------------------------------------
__global__ __launch_bounds__(512) void sortB_kernel(unsigned* __restrict__ binned,
                                                    const int* __restrict__ ofs,
                                                    int* __restrict__ ip0,
                                                    int* __restrict__ ip1,
                                                    unsigned short* __restrict__ c0a,
                                                    unsigned short* __restrict__ c1a) {
    __shared__ unsigned ent[ENT_CAP];
    __shared__ int cnt[256], pfx[256], cur[256];
    int t = threadIdx.x;
    int b = blockIdx.x;
    int start = ofs[b * NCHUNK];
    int end = ofs[(b + 1) * NCHUNK];
    int n = end - start;

    if (t < 256) cnt[t] = 0;
    __syncthreads();
    for (int i = t; i < n; i += 512) {
        unsigned u = binned[start + i];
        if (i < ENT_CAP) ent[i] = u;
        atomicAdd(&cnt[(u >> 17) & 255], 1);
    }
    __syncthreads();
    if (t < 256) pfx[t] = cnt[t];
    __syncthreads();
    for (int off = 1; off < 256; off <<= 1) {
        int add = (t < 256 && t >= off) ? pfx[t - off] : 0;
        __syncthreads();
        if (t < 256) pfx[t] += add;
        __syncthreads();
    }
    if (t < 256) {
        pfx[t] -= cnt[t];
        cur[t] = pfx[t];
    }
    __syncthreads();
    for (int i = t; i < n; i += 512) {
        if (i < ENT_CAP) {
            unsigned u = ent[i];
            int key = (u >> 17) & 255;
            int p = atomicAdd(&cur[key], 1);
            binned[start + p] = u & 0x1FFFF;
        }
    }
    if (t < 128) {
        int node = b * 128 + t;
        if (node < N_NODES) {
            ip0[node] = start + pfx[t];
            ip1[node] = start + pfx[t | 128];
            c0a[node] = (unsigned short)cnt[t];
            c1a[node] = (unsigned short)cnt[t | 128];
        }
    }
}

// ---------------------------------------------------------------------------
// Per-src-bucket out-degree counts from the byte-binned entries. Replaces
// 2.4M scattered global atomics with 2.4M LDS atomics + 200K clean stores.
// ---------------------------------------------------------------------------
__global__ __launch_bounds__(512) void countO_kernel(const unsigned char* __restrict__ binnedS,
                                                     const int* __restrict__ ofsS,
                                                     int* __restrict__ cntO0,
                                                     int* __restrict__ cntO1) {
    __shared__ int cnt[256];
    int t = threadIdx.x;
    int b = blockIdx.x;
    int start = ofsS[b * NCHUNK];
    int end = ofsS[(b + 1) * NCHUNK];
    if (t < 256) cnt[t] = 0;
    __syncthreads();
    for (int i = start + t; i < end; i += 512)
        atomicAdd(&cnt[(int)binnedS[i]], 1);
    __syncthreads();
    if (t < 128) {
        int node = b * 128 + t;
        if (node < N_NODES) {
            cntO0[node] = cnt[t];
            cntO1[node] = cnt[t | 128];
        }
    }
}

// ---------------------------------------------------------------------------
// Fused per-relation linears, 32 nodes/block; rsqrt(out-degree) inline.
// Output fp16 (gather operand for aggC).
// ---------------------------------------------------------------------------
__global__ __launch_bounds__(256) void lin2_kernel(const float* __restrict__ x,
                                                   const float* __restrict__ W0,
                                                   const float* __restrict__ W1,
                                                   const int* __restrict__ cntO0,
                                                   const int* __restrict__ cntO1,
                                                   __half* __restrict__ y0,
                                                   __half* __restrict__ y1) {
    __shared__ float W0l[64 * 64];
    __shared__ float W1l[64 * 64];
    __shared__ float xs[32][64];
    int t = threadIdx.x;
    for (int i = t; i < 64 * 64; i += 256) {
        W0l[i] = W0[i];
        W1l[i] = W1[i];
    }
    int base = blockIdx.x * 32;
    for (int i = t; i < 32 * 64; i += 256) {
        int node = base + (i >> 6);
        xs[i >> 6][i & 63] = (node < N_NODES) ? x[(size_t)node * 64 + (i & 63)] : 0.f;
    }
    __syncthreads();
    int w = t >> 6, j = t & 63;
    for (int r = 0; r < 8; ++r) {
        int local = w * 8 + r;
        int node = base + local;
        if (node >= N_NODES) break;
        float a0 = 0.f, a1 = 0.f;
#pragma unroll
        for (int k = 0; k < 64; ++k) {
            float xv = xs[local][k];
            a0 += xv * W0l[k * 64 + j];
            a1 += xv * W1l[k * 64 + j];
        }
        float r0 = rsqrtf((float)max(cntO0[node], 1));
        float r1 = rsqrtf((float)max(cntO1[node], 1));
        y0[(size_t)node * 64 + j] = __float2half_rn(a0 * r0);
        y1[(size_t)node * 64 + j] = __float2half_rn(a1 * r1);
    }
}

// ---------------------------------------------------------------------------
// Gather-aggregate (fp16 rows): one WAVE per dst node, eight 8-lane gather
// groups, each lane loads 16 B = 8 halves; f32 accumulate; rsI scale folded
// before a single 3-step butterfly; bias/ReLU fused.
// OUTH=0 -> f32 out (layer-1 h, consumed by lin2); OUTH=1 -> fp16 out (h2).
// ---------------------------------------------------------------------------
template <int RELU, int OUTH>
__global__ __launch_bounds__(256) void aggC_kernel(const __half* __restrict__ L0,
                                                   const __half* __restrict__ L1,
                                                   const unsigned* __restrict__ es,
                                                   const int* __restrict__ ip0,
                                                   const int* __restrict__ ip1,
                                                   const unsigned short* __restrict__ c0a,
                                                   const unsigned short* __restrict__ c1a,
                                                   const float* __restrict__ bia0,
                                                   const float* __restrict__ bia1,
                                                   float* __restrict__ outf,
                                                   __half* __restrict__ outh) {
    int t = threadIdx.x;
    int w = t >> 6, lane = t & 63;
    int g = lane >> 3, l8 = lane & 7;
    int node = blockIdx.x * 4 + w;
    if (node >= N_NODES) return;

    int st0 = ip0[node], c0 = c0a[node];
    int st1 = ip1[node], c1 = c1a[node];

    float a[8] = {0, 0, 0, 0, 0, 0, 0, 0};
    float b[8] = {0, 0, 0, 0, 0, 0, 0, 0};
    union HU { uint4 u; __half2 h[4]; };

    for (int k = g; k < c0; k += 8) {
        int s = (int)es[st0 + k];
        HU uu;
        uu.u = ((const uint4*)(L0 + (size_t)s * 64))[l8];
#pragma unroll
        for (int q = 0; q < 4; ++q) {
            float2 f = __half22float2(uu.h[q]);
            a[2 * q] += f.x;
            a[2 * q + 1] += f.y;
        }
    }
    for (int k = g; k < c1; k += 8) {
        int s = (int)es[st1 + k];
        HU uu;
        uu.u = ((const uint4*)(L1 + (size_t)s * 64))[l8];
#pragma unroll
        for (int q = 0; q < 4; ++q) {
            float2 f = __half22float2(uu.h[q]);
            b[2 * q] += f.x;
            b[2 * q + 1] += f.y;
        }
    }

    float r0 = rsqrtf((float)max(c0, 1));
    float r1 = rsqrtf((float)max(c1, 1));
    float o[8];
#pragma unroll
    for (int q = 0; q < 8; ++q) o[q] = a[q] * r0 + b[q] * r1;
#pragma unroll
    for (int q = 0; q < 8; ++q) {
        o[q] += __shfl_xor(o[q], 8);
        o[q] += __shfl_xor(o[q], 16);
        o[q] += __shfl_xor(o[q], 32);
    }

    if (g == 0) {
        float4 u0a = ((const float4*)bia0)[l8 * 2];
        float4 u0b = ((const float4*)bia0)[l8 * 2 + 1];
        float4 u1a = ((const float4*)bia1)[l8 * 2];
        float4 u1b = ((const float4*)bia1)[l8 * 2 + 1];
        o[0] += u0a.x + u1a.x; o[1] += u0a.y + u1a.y;
        o[2] += u0a.z + u1a.z; o[3] += u0a.w + u1a.w;
        o[4] += u0b.x + u1b.x; o[5] += u0b.y + u1b.y;
        o[6] += u0b.z + u1b.z; o[7] += u0b.w + u1b.w;
        if (RELU) {
#pragma unroll
            for (int q = 0; q < 8; ++q) o[q] = fmaxf(o[q], 0.f);
        }
        if (OUTH) {
            HU vv;
#pragma unroll
            for (int q = 0; q < 4; ++q)
                vv.h[q] = __floats2half2_rn(o[2 * q], o[2 * q + 1]);
            ((uint4*)(outh + (size_t)node * 64))[l8] = vv.u;
        } else {
            float4 f0 = {o[0], o[1], o[2], o[3]};
            float4 f1 = {o[4], o[5], o[6], o[7]};
            ((float4*)(outf + (size_t)node * 64))[l8 * 2] = f0;
            ((float4*)(outf + (size_t)node * 64))[l8 * 2 + 1] = f1;
        }
    }
}

// ---------------------------------------------------------------------------
// Edge dot products on fp16 h2: 8 threads/edge, 16 B loads, f32 accumulate.
// ---------------------------------------------------------------------------
__global__ __launch_bounds__(256) void score_kernel(const __half* __restrict__ h2,
                                                    const int* __restrict__ ps,
                                                    const int* __restrict__ pd,
                                                    const int* __restrict__ ns,
                                                    const int* __restrict__ nd,
                                                    float* __restrict__ out) {
    int gid = blockIdx.x * blockDim.x + threadIdx.x;
    int e = gid >> 3;
    int l8 = gid & 7;
    if (e >= 2 * N_EDGES) return;
    int s, d;
    if (e < N_EDGES) { s = ps[e]; d = pd[e]; }
    else             { s = ns[e - N_EDGES]; d = nd[e - N_EDGES]; }
    union HU { uint4 u; __half2 h[4]; };
    HU ua, ub;
    ua.u = ((const uint4*)(h2 + (size_t)s * 64))[l8];
    ub.u = ((const uint4*)(h2 + (size_t)d * 64))[l8];
    float p = 0.f;
#pragma unroll
    for (int q = 0; q < 4; ++q) {
        float2 fa = __half22float2(ua.h[q]);
        float2 fb = __half22float2(ub.h[q]);
        p += fa.x * fb.x + fa.y * fb.y;
    }
    p += __shfl_xor(p, 1);
    p += __shfl_xor(p, 2);
    p += __shfl_xor(p, 4);
    if (l8 == 0) out[e] = p;
}

extern "C" void kernel_launch(void* const* d_in, const int* in_sizes, int n_in,
                              void* d_out, int out_size, void* d_ws, size_t ws_size,
                              hipStream_t stream) {
    const float* x    = (const float*)d_in[0];
    const int* s0     = (const int*)d_in[1];
    const int* d0     = (const int*)d_in[2];
    const int* s1     = (const int*)d_in[3];
    const int* d1     = (const int*)d_in[4];
    const int* nsrc   = (const int*)d_in[5];
    const int* ndst   = (const int*)d_in[6];
    const float* W1_0 = (const float*)d_in[7];
    const float* W1_1 = (const float*)d_in[8];
    const float* W2_0 = (const float*)d_in[9];
    const float* W2_1 = (const float*)d_in[10];
    const float* b1_0 = (const float*)d_in[11];
    const float* b1_1 = (const float*)d_in[12];
    const float* b2_0 = (const float*)d_in[13];
    const float* b2_1 = (const float*)d_in[14];
    float* out = (float*)d_out;

    // ---- workspace ----
    char* p = (char*)d_ws;
    int* cntO0 = (int*)p;      p += N_NODES * 4;
    int* cntO1 = (int*)p;      p += N_NODES * 4;
    int* hist  = (int*)p;      p += 2 * HIST_L * 4;          // dst half + src half
    int* ofs   = (int*)p;      p += (HIST_L + 1) * 4;
    int* ofsS  = (int*)p;      p += (HIST_L + 1) * 4;
    int* bsum  = (int*)p;      p += 1024 * 4;
    unsigned* binned = (unsigned*)p;  p += (size_t)TOTAL_E * 4;
    int* ip0   = (int*)p;      p += N_NODES * 4;
    int* ip1   = (int*)p;      p += N_NODES * 4;
    unsigned short* c0a = (unsigned short*)p;  p += N_NODES * 2;
    unsigned short* c1a = (unsigned short*)p;  p += N_NODES * 2;
    unsigned char* binnedS = (unsigned char*)p;  p += (size_t)TOTAL_E;
    p = (char*)(((size_t)p + 255) & ~(size_t)255);
    __half* bufL0h = (__half*)p;  p += (size_t)N_NODES * D * 2;
    __half* bufL1h = (__half*)p;  p += (size_t)N_NODES * D * 2;
    __half* h2h    = (__half*)p;  p += (size_t)N_NODES * D * 2;
    p = (char*)(((size_t)p + 255) & ~(size_t)255);
    float* bufH = (float*)p;   p += (size_t)N_NODES * D * 4;

    const int linGrid  = (N_NODES + 31) / 32;
    const int aggGrid  = (N_NODES + 3) / 4;
    const int scorGrid = (2 * N_EDGES * 8) / 256;

    // ---- degrees + binning (no per-edge global atomics anywhere) ----
    countA_kernel<<<NCHUNK, 512, 0, stream>>>(s0, d0, s1, d1, hist);
    scan1_kernel<<<SCAN_NB, SCAN_BS, 0, stream>>>(hist, ofs, bsum);
    scan2_kernel<<<1, 1024, 0, stream>>>(bsum);
    scan3_kernel<<<SCAN_NB, SCAN_BS, 0, stream>>>(ofs, bsum);
    scan1_kernel<<<SCAN_NB, SCAN_BS, 0, stream>>>(hist + HIST_L, ofsS, bsum);
    scan2_kernel<<<1, 1024, 0, stream>>>(bsum);
    scan3_kernel<<<SCAN_NB, SCAN_BS, 0, stream>>>(ofsS, bsum);
    scatterA_kernel<<<NCHUNK, 512, 0, stream>>>(s0, d0, s1, d1, ofs, ofsS, binned, binnedS);
    sortB_kernel<<<NBUCK, 512, 0, stream>>>(binned, ofs, ip0, ip1, c0a, c1a);
    countO_kernel<<<NBUCK, 512, 0, stream>>>(binnedS, ofsS, cntO0, cntO1);

    // ---- layer 1 ----
    lin2_kernel<<<linGrid, 256, 0, stream>>>(x, W1_0, W1_1, cntO0, cntO1, bufL0h, bufL1h);
    aggC_kernel<1, 0><<<aggGrid, 256, 0, stream>>>(bufL0h, bufL1h, binned, ip0, ip1,
                                                   c0a, c1a, b1_0, b1_1, bufH, nullptr);

    // ---- layer 2 ----
    lin2_kernel<<<linGrid, 256, 0, stream>>>(bufH, W2_0, W2_1, cntO0, cntO1, bufL0h, bufL1h);
    aggC_kernel<0, 1><<<aggGrid, 256, 0, stream>>>(bufL0h, bufL1h, binned, ip0, ip1,
                                                   c0a, c1a, b2_0, b2_1, nullptr, h2h);

    // ---- scores ----
    score_kernel<<<scorGrid, 256, 0, stream>>>(h2h, s0, d0, nsrc, ndst, out);
}

// Round 2
// 347.054 us; speedup vs baseline: 1.4134x; 1.2832x over previous
//
#include <hip/hip_runtime.h>
#include <hip/hip_fp16.h>

#define N_NODES 100000
#define N_EDGES 1200000
#define TOTAL_E (2 * N_EDGES)
#define D 64

#define BSH 7                       // bucket = node >> 7 (128 nodes/bucket)
#define NBUCK 782                   // ceil(100000/128)
#define NCHUNK 320
#define CHUNK 7500                  // NCHUNK * CHUNK == TOTAL_E
#define HIST_L (NBUCK * NCHUNK)     // 250240 (per side; hist array holds 2x)
#define SCAN_BS 256
#define SCAN_NB ((HIST_L + SCAN_BS - 1) / SCAN_BS)  // 978
#define ENT_CAP 4608                // bucket mean 3072, sigma 55 -> +28 sigma
#define L2M_GRID ((N_NODES + 127) / 128)  // 782

typedef __attribute__((ext_vector_type(8))) short bf16x8;
typedef __attribute__((ext_vector_type(4))) float f32x4;

__device__ __forceinline__ unsigned short f32_bf16_rne(float f) {
    unsigned u = __float_as_uint(f);
    unsigned r = u + 0x7FFF + ((u >> 16) & 1);
    return (unsigned short)(r >> 16);
}
__device__ __forceinline__ float bf16_f32(unsigned short h) {
    return __uint_as_float(((unsigned)h) << 16);
}

// ---------------------------------------------------------------------------
// Per-chunk LDS histograms of dst buckets AND src buckets. No global atomics.
// hist layout: [0, HIST_L) = dst-side, [HIST_L, 2*HIST_L) = src-side.
// ---------------------------------------------------------------------------
__global__ __launch_bounds__(512) void countA_kernel(const int* __restrict__ s0,
                                                     const int* __restrict__ d0,
                                                     const int* __restrict__ s1,
                                                     const int* __restrict__ d1,
                                                     int* __restrict__ hist) {
    __shared__ int hD[NBUCK];
    __shared__ int hS[NBUCK];
    int t = threadIdx.x;
    for (int i = t; i < NBUCK; i += 512) { hD[i] = 0; hS[i] = 0; }
    __syncthreads();
    int base = blockIdx.x * CHUNK;
    for (int i = t; i < CHUNK; i += 512) {
        int e = base + i;
        int rel = (e >= N_EDGES);
        int src = rel ? s1[e - N_EDGES] : s0[e];
        int dst = rel ? d1[e - N_EDGES] : d0[e];
        atomicAdd(&hD[dst >> BSH], 1);
        atomicAdd(&hS[src >> BSH], 1);
    }
    __syncthreads();
    for (int i = t; i < NBUCK; i += 512) {
        hist[i * NCHUNK + blockIdx.x] = hD[i];
        hist[HIST_L + i * NCHUNK + blockIdx.x] = hS[i];
    }
}

// ---------------------------------------------------------------------------
// Exclusive scan over HIST_L ints (invoked twice: dst half, src half).
// ---------------------------------------------------------------------------
__global__ void scan1_kernel(const int* __restrict__ in, int* __restrict__ out,
                             int* __restrict__ bsum) {
    __shared__ int s[SCAN_BS];
    int t = threadIdx.x;
    int i = blockIdx.x * SCAN_BS + t;
    int v = (i < HIST_L) ? in[i] : 0;
    s[t] = v;
    __syncthreads();
    for (int off = 1; off < SCAN_BS; off <<= 1) {
        int add = (t >= off) ? s[t - off] : 0;
        __syncthreads();
        s[t] += add;
        __syncthreads();
    }
    if (i < HIST_L) out[i] = s[t] - v;
    if (t == SCAN_BS - 1) bsum[blockIdx.x] = s[t];
}

__global__ void scan2_kernel(int* __restrict__ bsum) {
    __shared__ int s[1024];
    int t = threadIdx.x;
    int v = (t < SCAN_NB) ? bsum[t] : 0;
    s[t] = v;
    __syncthreads();
    for (int off = 1; off < 1024; off <<= 1) {
        int add = (t >= off) ? s[t - off] : 0;
        __syncthreads();
        s[t] += add;
        __syncthreads();
    }
    if (t < SCAN_NB) bsum[t] = s[t] - v;
}

__global__ void scan3_kernel(int* __restrict__ out, const int* __restrict__ bsum) {
    int i = blockIdx.x * SCAN_BS + threadIdx.x;
    if (i < HIST_L) out[i] += bsum[blockIdx.x];
    if (i == 0) out[HIST_L] = TOTAL_E;
}

// ---------------------------------------------------------------------------
// Scatter packed entries into bucket-binned arrays.
// dst entry (u32) = src | dl<<17 | rel<<24  -> binned
// src entry (u8)  = sl | rel<<7             -> binnedS (for out-degree counts)
// ---------------------------------------------------------------------------
__global__ __launch_bounds__(512) void scatterA_kernel(const int* __restrict__ s0,
                                                       const int* __restrict__ d0,
                                                       const int* __restrict__ s1,
                                                       const int* __restrict__ d1,
                                                       const int* __restrict__ ofs,
                                                       const int* __restrict__ ofsS,
                                                       unsigned* __restrict__ binned,
                                                       unsigned char* __restrict__ binnedS) {
    __shared__ int cur[NBUCK];
    __shared__ int curS[NBUCK];
    int t = threadIdx.x, wg = blockIdx.x;
    for (int b = t; b < NBUCK; b += 512) {
        cur[b] = ofs[b * NCHUNK + wg];
        curS[b] = ofsS[b * NCHUNK + wg];
    }
    __syncthreads();
    int base = wg * CHUNK;
    for (int i = t; i < CHUNK; i += 512) {
        int e = base + i;
        int rel = (e >= N_EDGES);
        int src = rel ? s1[e - N_EDGES] : s0[e];
        int dst = rel ? d1[e - N_EDGES] : d0[e];
        int p = atomicAdd(&cur[dst >> BSH], 1);
        binned[p] = (unsigned)src | ((unsigned)(dst & 127) << 17) | ((unsigned)rel << 24);
        int q = atomicAdd(&curS[src >> BSH], 1);
        binnedS[q] = (unsigned char)((src & 127) | (rel << 7));
    }
}

// ---------------------------------------------------------------------------
// Per-bucket LDS counting sort (in place): binned -> src indices grouped by
// key = dl | rel<<7; per-(node,rel) offsets/counts.
// ---------------------------------------------------------------------------
__global__ __launch_bounds__(512) void sortB_kernel(unsigned* __restrict__ binned,
                                                    const int* __restrict__ ofs,
                                                    int* __restrict__ ip0,
                                                    int* __restrict__ ip1,
                                                    unsigned short* __restrict__ c0a,
                                                    unsigned short* __restrict__ c1a) {
    __shared__ unsigned ent[ENT_CAP];
    __shared__ int cnt[256], pfx[256], cur[256];
    int t = threadIdx.x;
    int b = blockIdx.x;
    int start = ofs[b * NCHUNK];
    int end = ofs[(b + 1) * NCHUNK];
    int n = end - start;

    if (t < 256) cnt[t] = 0;
    __syncthreads();
    for (int i = t; i < n; i += 512) {
        unsigned u = binned[start + i];
        if (i < ENT_CAP) ent[i] = u;
        atomicAdd(&cnt[(u >> 17) & 255], 1);
    }
    __syncthreads();
    if (t < 256) pfx[t] = cnt[t];
    __syncthreads();
    for (int off = 1; off < 256; off <<= 1) {
        int add = (t < 256 && t >= off) ? pfx[t - off] : 0;
        __syncthreads();
        if (t < 256) pfx[t] += add;
        __syncthreads();
    }
    if (t < 256) {
        pfx[t] -= cnt[t];
        cur[t] = pfx[t];
    }
    __syncthreads();
    for (int i = t; i < n; i += 512) {
        if (i < ENT_CAP) {
            unsigned u = ent[i];
            int key = (u >> 17) & 255;
            int p = atomicAdd(&cur[key], 1);
            binned[start + p] = u & 0x1FFFF;
        }
    }
    if (t < 128) {
        int node = b * 128 + t;
        if (node < N_NODES) {
            ip0[node] = start + pfx[t];
            ip1[node] = start + pfx[t | 128];
            c0a[node] = (unsigned short)cnt[t];
            c1a[node] = (unsigned short)cnt[t | 128];
        }
    }
}

// ---------------------------------------------------------------------------
// Per-src-bucket out-degree counts from the byte-binned entries.
// ---------------------------------------------------------------------------
__global__ __launch_bounds__(512) void countO_kernel(const unsigned char* __restrict__ binnedS,
                                                     const int* __restrict__ ofsS,
                                                     int* __restrict__ cntO0,
                                                     int* __restrict__ cntO1) {
    __shared__ int cnt[256];
    int t = threadIdx.x;
    int b = blockIdx.x;
    int start = ofsS[b * NCHUNK];
    int end = ofsS[(b + 1) * NCHUNK];
    if (t < 256) cnt[t] = 0;
    __syncthreads();
    for (int i = start + t; i < end; i += 512)
        atomicAdd(&cnt[(int)binnedS[i]], 1);
    __syncthreads();
    if (t < 128) {
        int node = b * 128 + t;
        if (node < N_NODES) {
            cntO0[node] = cnt[t];
            cntO1[node] = cnt[t | 128];
        }
    }
}

// ---------------------------------------------------------------------------
// Pre-split W into bf16 hi/lo MFMA B-fragments, per-lane contiguous order:
// Wf[rel][hl][kstep][g][col][j], element (k = kstep*32 + g*8 + j, col).
// ---------------------------------------------------------------------------
__global__ void wprep_kernel(const float* __restrict__ W0,
                             const float* __restrict__ W1,
                             short* __restrict__ Wf) {
    int t = blockIdx.x * blockDim.x + threadIdx.x;
    if (t >= 2 * 4096) return;
    int rel = t >> 12;
    int e = t & 4095;
    int k = e >> 6, col = e & 63;
    float wv = (rel ? W1 : W0)[e];
    unsigned short hi = f32_bf16_rne(wv);
    unsigned short lo = f32_bf16_rne(wv - bf16_f32(hi));
    int kstep = k >> 5, g = (k >> 3) & 3, j = k & 7;
    int base = ((((rel * 2 + 0) * 2 + kstep) * 4 + g) * 64 + col) * 8 + j;
    int baseL = ((((rel * 2 + 1) * 2 + kstep) * 4 + g) * 64 + col) * 8 + j;
    Wf[base] = (short)hi;
    Wf[baseL] = (short)lo;
}

// ---------------------------------------------------------------------------
// MFMA linears: Y0 = (X@W0)*rsqrt(degO0), Y1 = (X@W1)*rsqrt(degO1), fp16 out.
// Split-bf16 (hi+lo, 3 MFMAs) keeps error ~2^-15 rel — below the fp16 output
// ulp that dominates absmax. 128 rows/block, 4 waves, 2 m-tiles/wave.
// A and B fragments use the same (g,j)->k mapping (k = kstep*32+g*8+j), so
// the result is invariant to the HW's internal k permutation. C/D layout:
// col=lane&15, row=(lane>>4)*4+reg (HW-verified).  No LDS, no barriers.
// ---------------------------------------------------------------------------
__global__ __launch_bounds__(256) void lin2m_kernel(const float* __restrict__ x,
                                                    const short* __restrict__ Wf,
                                                    const int* __restrict__ cntO0,
                                                    const int* __restrict__ cntO1,
                                                    __half* __restrict__ y0,
                                                    __half* __restrict__ y1) {
    int t = threadIdx.x;
    int w = t >> 6, lane = t & 63;
    int lr = lane & 15, g = lane >> 4;
    int rowbase = blockIdx.x * 128 + w * 32;

    // Load + convert A fragments: 2 m-tiles x 2 k-steps, hi/lo.
    bf16x8 ah[2][2], al[2][2];
#pragma unroll
    for (int m = 0; m < 2; ++m) {
        int row = rowbase + m * 16 + lr;
        bool ok = row < N_NODES;
        const float* xp = x + (size_t)row * 64 + g * 8;
#pragma unroll
        for (int s = 0; s < 2; ++s) {
            float fv[8];
            if (ok) {
                float4 f0 = ((const float4*)(xp + s * 32))[0];
                float4 f1 = ((const float4*)(xp + s * 32))[1];
                fv[0] = f0.x; fv[1] = f0.y; fv[2] = f0.z; fv[3] = f0.w;
                fv[4] = f1.x; fv[5] = f1.y; fv[6] = f1.z; fv[7] = f1.w;
            } else {
#pragma unroll
                for (int j = 0; j < 8; ++j) fv[j] = 0.f;
            }
#pragma unroll
            for (int j = 0; j < 8; ++j) {
                unsigned short hi = f32_bf16_rne(fv[j]);
                unsigned short lo = f32_bf16_rne(fv[j] - bf16_f32(hi));
                ah[m][s][j] = (short)hi;
                al[m][s][j] = (short)lo;
            }
        }
    }

    // Degree scales for the rows this lane STORES (C-row = g*4+reg).
    float rsc[2][2][4];
#pragma unroll
    for (int m = 0; m < 2; ++m)
#pragma unroll
        for (int reg = 0; reg < 4; ++reg) {
            int row = rowbase + m * 16 + g * 4 + reg;
            bool ok = row < N_NODES;
            rsc[0][m][reg] = ok ? rsqrtf((float)max(cntO0[row], 1)) : 1.f;
            rsc[1][m][reg] = ok ? rsqrtf((float)max(cntO1[row], 1)) : 1.f;
        }

#pragma unroll
    for (int rel = 0; rel < 2; ++rel) {
        __half* yo = rel ? y1 : y0;
        const short* wr = Wf + rel * 8192 + g * 512 + (4 * 16 + 0) * 0;  // base per rel/g
#pragma unroll
        for (int n = 0; n < 4; ++n) {
            const short* wb = wr + (n * 16 + lr) * 8;
            bf16x8 wh0 = *(const bf16x8*)(wb);          // hl=0, kstep=0
            bf16x8 wh1 = *(const bf16x8*)(wb + 2048);   // hl=0, kstep=1
            bf16x8 wl0 = *(const bf16x8*)(wb + 4096);   // hl=1, kstep=0
            bf16x8 wl1 = *(const bf16x8*)(wb + 6144);   // hl=1, kstep=1
#pragma unroll
            for (int m = 0; m < 2; ++m) {
                f32x4 acc = {0.f, 0.f, 0.f, 0.f};
                acc = __builtin_amdgcn_mfma_f32_16x16x32_bf16(al[m][0], wh0, acc, 0, 0, 0);
                acc = __builtin_amdgcn_mfma_f32_16x16x32_bf16(ah[m][0], wl0, acc, 0, 0, 0);
                acc = __builtin_amdgcn_mfma_f32_16x16x32_bf16(ah[m][0], wh0, acc, 0, 0, 0);
                acc = __builtin_amdgcn_mfma_f32_16x16x32_bf16(al[m][1], wh1, acc, 0, 0, 0);
                acc = __builtin_amdgcn_mfma_f32_16x16x32_bf16(ah[m][1], wl1, acc, 0, 0, 0);
                acc = __builtin_amdgcn_mfma_f32_16x16x32_bf16(ah[m][1], wh1, acc, 0, 0, 0);
#pragma unroll
                for (int reg = 0; reg < 4; ++reg) {
                    int row = rowbase + m * 16 + g * 4 + reg;
                    if (row < N_NODES)
                        yo[(size_t)row * 64 + n * 16 + lr] =
                            __float2half_rn(acc[reg] * rsc[rel][m][reg]);
                }
            }
        }
    }
}

// ---------------------------------------------------------------------------
// Gather-aggregate (fp16 rows): one WAVE per dst node, eight 8-lane gather
// groups; f32 accumulate; rsI folded; bias/ReLU fused.
// ---------------------------------------------------------------------------
template <int RELU, int OUTH>
__global__ __launch_bounds__(256) void aggC_kernel(const __half* __restrict__ L0,
                                                   const __half* __restrict__ L1,
                                                   const unsigned* __restrict__ es,
                                                   const int* __restrict__ ip0,
                                                   const int* __restrict__ ip1,
                                                   const unsigned short* __restrict__ c0a,
                                                   const unsigned short* __restrict__ c1a,
                                                   const float* __restrict__ bia0,
                                                   const float* __restrict__ bia1,
                                                   float* __restrict__ outf,
                                                   __half* __restrict__ outh) {
    int t = threadIdx.x;
    int w = t >> 6, lane = t & 63;
    int g = lane >> 3, l8 = lane & 7;
    int node = blockIdx.x * 4 + w;
    if (node >= N_NODES) return;

    int st0 = ip0[node], c0 = c0a[node];
    int st1 = ip1[node], c1 = c1a[node];

    float a[8] = {0, 0, 0, 0, 0, 0, 0, 0};
    float b[8] = {0, 0, 0, 0, 0, 0, 0, 0};
    union HU { uint4 u; __half2 h[4]; };

    for (int k = g; k < c0; k += 8) {
        int s = (int)es[st0 + k];
        HU uu;
        uu.u = ((const uint4*)(L0 + (size_t)s * 64))[l8];
#pragma unroll
        for (int q = 0; q < 4; ++q) {
            float2 f = __half22float2(uu.h[q]);
            a[2 * q] += f.x;
            a[2 * q + 1] += f.y;
        }
    }
    for (int k = g; k < c1; k += 8) {
        int s = (int)es[st1 + k];
        HU uu;
        uu.u = ((const uint4*)(L1 + (size_t)s * 64))[l8];
#pragma unroll
        for (int q = 0; q < 4; ++q) {
            float2 f = __half22float2(uu.h[q]);
            b[2 * q] += f.x;
            b[2 * q + 1] += f.y;
        }
    }

    float r0 = rsqrtf((float)max(c0, 1));
    float r1 = rsqrtf((float)max(c1, 1));
    float o[8];
#pragma unroll
    for (int q = 0; q < 8; ++q) o[q] = a[q] * r0 + b[q] * r1;
#pragma unroll
    for (int q = 0; q < 8; ++q) {
        o[q] += __shfl_xor(o[q], 8);
        o[q] += __shfl_xor(o[q], 16);
        o[q] += __shfl_xor(o[q], 32);
    }

    if (g == 0) {
        float4 u0a = ((const float4*)bia0)[l8 * 2];
        float4 u0b = ((const float4*)bia0)[l8 * 2 + 1];
        float4 u1a = ((const float4*)bia1)[l8 * 2];
        float4 u1b = ((const float4*)bia1)[l8 * 2 + 1];
        o[0] += u0a.x + u1a.x; o[1] += u0a.y + u1a.y;
        o[2] += u0a.z + u1a.z; o[3] += u0a.w + u1a.w;
        o[4] += u0b.x + u1b.x; o[5] += u0b.y + u1b.y;
        o[6] += u0b.z + u1b.z; o[7] += u0b.w + u1b.w;
        if (RELU) {
#pragma unroll
            for (int q = 0; q < 8; ++q) o[q] = fmaxf(o[q], 0.f);
        }
        if (OUTH) {
            HU vv;
#pragma unroll
            for (int q = 0; q < 4; ++q)
                vv.h[q] = __floats2half2_rn(o[2 * q], o[2 * q + 1]);
            ((uint4*)(outh + (size_t)node * 64))[l8] = vv.u;
        } else {
            float4 f0 = {o[0], o[1], o[2], o[3]};
            float4 f1 = {o[4], o[5], o[6], o[7]};
            ((float4*)(outf + (size_t)node * 64))[l8 * 2] = f0;
            ((float4*)(outf + (size_t)node * 64))[l8 * 2 + 1] = f1;
        }
    }
}

// ---------------------------------------------------------------------------
// Edge dot products on fp16 h2: 8 threads/edge, 16 B loads, f32 accumulate.
// ---------------------------------------------------------------------------
__global__ __launch_bounds__(256) void score_kernel(const __half* __restrict__ h2,
                                                    const int* __restrict__ ps,
                                                    const int* __restrict__ pd,
                                                    const int* __restrict__ ns,
                                                    const int* __restrict__ nd,
                                                    float* __restrict__ out) {
    int gid = blockIdx.x * blockDim.x + threadIdx.x;
    int e = gid >> 3;
    int l8 = gid & 7;
    if (e >= 2 * N_EDGES) return;
    int s, d;
    if (e < N_EDGES) { s = ps[e]; d = pd[e]; }
    else             { s = ns[e - N_EDGES]; d = nd[e - N_EDGES]; }
    union HU { uint4 u; __half2 h[4]; };
    HU ua, ub;
    ua.u = ((const uint4*)(h2 + (size_t)s * 64))[l8];
    ub.u = ((const uint4*)(h2 + (size_t)d * 64))[l8];
    float p = 0.f;
#pragma unroll
    for (int q = 0; q < 4; ++q) {
        float2 fa = __half22float2(ua.h[q]);
        float2 fb = __half22float2(ub.h[q]);
        p += fa.x * fb.x + fa.y * fb.y;
    }
    p += __shfl_xor(p, 1);
    p += __shfl_xor(p, 2);
    p += __shfl_xor(p, 4);
    if (l8 == 0) out[e] = p;
}

extern "C" void kernel_launch(void* const* d_in, const int* in_sizes, int n_in,
                              void* d_out, int out_size, void* d_ws, size_t ws_size,
                              hipStream_t stream) {
    const float* x    = (const float*)d_in[0];
    const int* s0     = (const int*)d_in[1];
    const int* d0     = (const int*)d_in[2];
    const int* s1     = (const int*)d_in[3];
    const int* d1     = (const int*)d_in[4];
    const int* nsrc   = (const int*)d_in[5];
    const int* ndst   = (const int*)d_in[6];
    const float* W1_0 = (const float*)d_in[7];
    const float* W1_1 = (const float*)d_in[8];
    const float* W2_0 = (const float*)d_in[9];
    const float* W2_1 = (const float*)d_in[10];
    const float* b1_0 = (const float*)d_in[11];
    const float* b1_1 = (const float*)d_in[12];
    const float* b2_0 = (const float*)d_in[13];
    const float* b2_1 = (const float*)d_in[14];
    float* out = (float*)d_out;

    // ---- workspace ----
    char* p = (char*)d_ws;
    int* cntO0 = (int*)p;      p += N_NODES * 4;
    int* cntO1 = (int*)p;      p += N_NODES * 4;
    int* hist  = (int*)p;      p += 2 * HIST_L * 4;          // dst half + src half
    int* ofs   = (int*)p;      p += (HIST_L + 1) * 4;
    int* ofsS  = (int*)p;      p += (HIST_L + 1) * 4;
    int* bsum  = (int*)p;      p += 1024 * 4;
    unsigned* binned = (unsigned*)p;  p += (size_t)TOTAL_E * 4;
    int* ip0   = (int*)p;      p += N_NODES * 4;
    int* ip1   = (int*)p;      p += N_NODES * 4;
    unsigned short* c0a = (unsigned short*)p;  p += N_NODES * 2;
    unsigned short* c1a = (unsigned short*)p;  p += N_NODES * 2;
    unsigned char* binnedS = (unsigned char*)p;  p += (size_t)TOTAL_E;
    p = (char*)(((size_t)p + 255) & ~(size_t)255);
    short* WfA = (short*)p;    p += 16384 * 2;               // layer-1 W frags
    short* WfB = (short*)p;    p += 16384 * 2;               // layer-2 W frags
    p = (char*)(((size_t)p + 255) & ~(size_t)255);
    __half* bufL0h = (__half*)p;  p += (size_t)N_NODES * D * 2;
    __half* bufL1h = (__half*)p;  p += (size_t)N_NODES * D * 2;
    __half* h2h    = (__half*)p;  p += (size_t)N_NODES * D * 2;
    p = (char*)(((size_t)p + 255) & ~(size_t)255);
    float* bufH = (float*)p;   p += (size_t)N_NODES * D * 4;

    const int aggGrid  = (N_NODES + 3) / 4;
    const int scorGrid = (2 * N_EDGES * 8) / 256;

    // ---- W fragment prep (tiny, overlaps nothing critical) ----
    wprep_kernel<<<32, 256, 0, stream>>>(W1_0, W1_1, WfA);
    wprep_kernel<<<32, 256, 0, stream>>>(W2_0, W2_1, WfB);

    // ---- degrees + binning (no per-edge global atomics anywhere) ----
    countA_kernel<<<NCHUNK, 512, 0, stream>>>(s0, d0, s1, d1, hist);
    scan1_kernel<<<SCAN_NB, SCAN_BS, 0, stream>>>(hist, ofs, bsum);
    scan2_kernel<<<1, 1024, 0, stream>>>(bsum);
    scan3_kernel<<<SCAN_NB, SCAN_BS, 0, stream>>>(ofs, bsum);
    scan1_kernel<<<SCAN_NB, SCAN_BS, 0, stream>>>(hist + HIST_L, ofsS, bsum);
    scan2_kernel<<<1, 1024, 0, stream>>>(bsum);
    scan3_kernel<<<SCAN_NB, SCAN_BS, 0, stream>>>(ofsS, bsum);
    scatterA_kernel<<<NCHUNK, 512, 0, stream>>>(s0, d0, s1, d1, ofs, ofsS, binned, binnedS);
    sortB_kernel<<<NBUCK, 512, 0, stream>>>(binned, ofs, ip0, ip1, c0a, c1a);
    countO_kernel<<<NBUCK, 512, 0, stream>>>(binnedS, ofsS, cntO0, cntO1);

    // ---- layer 1 ----
    lin2m_kernel<<<L2M_GRID, 256, 0, stream>>>(x, WfA, cntO0, cntO1, bufL0h, bufL1h);
    aggC_kernel<1, 0><<<aggGrid, 256, 0, stream>>>(bufL0h, bufL1h, binned, ip0, ip1,
                                                   c0a, c1a, b1_0, b1_1, bufH, nullptr);

    // ---- layer 2 ----
    lin2m_kernel<<<L2M_GRID, 256, 0, stream>>>(bufH, WfB, cntO0, cntO1, bufL0h, bufL1h);
    aggC_kernel<0, 1><<<aggGrid, 256, 0, stream>>>(bufL0h, bufL1h, binned, ip0, ip1,
                                                   c0a, c1a, b2_0, b2_1, nullptr, h2h);

    // ---- scores ----
    score_kernel<<<scorGrid, 256, 0, stream>>>(h2h, s0, d0, nsrc, ndst, out);
}

// Round 3
// 340.515 us; speedup vs baseline: 1.4406x; 1.0192x over previous
//
#include <hip/hip_runtime.h>
#include <hip/hip_fp16.h>

#define N_NODES 100000
#define N_EDGES 1200000
#define TOTAL_E (2 * N_EDGES)
#define D 64

#define BSH 7                       // bucket = node >> 7 (128 nodes/bucket)
#define NBUCK 782                   // ceil(100000/128)
#define NCHUNK 320
#define CHUNK 7500                  // NCHUNK * CHUNK == TOTAL_E
#define HIST_L (NBUCK * NCHUNK)     // 250240 (per side; hist array holds 2x)
#define SCAN_BS 256
#define SCAN_NB ((HIST_L + SCAN_BS - 1) / SCAN_BS)  // 978
#define ENT_CAP 4608                // bucket mean 3072, sigma 55 -> +28 sigma
#define L2M_GRID ((N_NODES + 127) / 128)  // 782
#define NKEY 2048                   // sortB key space: rel(1) | dl(7) | src_super(3)

typedef __attribute__((ext_vector_type(8))) short bf16x8;
typedef __attribute__((ext_vector_type(4))) float f32x4;

__device__ __forceinline__ unsigned short f32_bf16_rne(float f) {
    unsigned u = __float_as_uint(f);
    unsigned r = u + 0x7FFF + ((u >> 16) & 1);
    return (unsigned short)(r >> 16);
}
__device__ __forceinline__ float bf16_f32(unsigned short h) {
    return __uint_as_float(((unsigned)h) << 16);
}

// ---------------------------------------------------------------------------
// Per-chunk LDS histograms of dst buckets AND src buckets. No global atomics.
// hist layout: [0, HIST_L) = dst-side, [HIST_L, 2*HIST_L) = src-side.
// ---------------------------------------------------------------------------
__global__ __launch_bounds__(512) void countA_kernel(const int* __restrict__ s0,
                                                     const int* __restrict__ d0,
                                                     const int* __restrict__ s1,
                                                     const int* __restrict__ d1,
                                                     int* __restrict__ hist) {
    __shared__ int hD[NBUCK];
    __shared__ int hS[NBUCK];
    int t = threadIdx.x;
    for (int i = t; i < NBUCK; i += 512) { hD[i] = 0; hS[i] = 0; }
    __syncthreads();
    int base = blockIdx.x * CHUNK;
    for (int i = t; i < CHUNK; i += 512) {
        int e = base + i;
        int rel = (e >= N_EDGES);
        int src = rel ? s1[e - N_EDGES] : s0[e];
        int dst = rel ? d1[e - N_EDGES] : d0[e];
        atomicAdd(&hD[dst >> BSH], 1);
        atomicAdd(&hS[src >> BSH], 1);
    }
    __syncthreads();
    for (int i = t; i < NBUCK; i += 512) {
        hist[i * NCHUNK + blockIdx.x] = hD[i];
        hist[HIST_L + i * NCHUNK + blockIdx.x] = hS[i];
    }
}

// ---------------------------------------------------------------------------
// Exclusive scan over HIST_L ints (invoked twice: dst half, src half).
// ---------------------------------------------------------------------------
__global__ void scan1_kernel(const int* __restrict__ in, int* __restrict__ out,
                             int* __restrict__ bsum) {
    __shared__ int s[SCAN_BS];
    int t = threadIdx.x;
    int i = blockIdx.x * SCAN_BS + t;
    int v = (i < HIST_L) ? in[i] : 0;
    s[t] = v;
    __syncthreads();
    for (int off = 1; off < SCAN_BS; off <<= 1) {
        int add = (t >= off) ? s[t - off] : 0;
        __syncthreads();
        s[t] += add;
        __syncthreads();
    }
    if (i < HIST_L) out[i] = s[t] - v;
    if (t == SCAN_BS - 1) bsum[blockIdx.x] = s[t];
}

__global__ void scan2_kernel(int* __restrict__ bsum) {
    __shared__ int s[1024];
    int t = threadIdx.x;
    int v = (t < SCAN_NB) ? bsum[t] : 0;
    s[t] = v;
    __syncthreads();
    for (int off = 1; off < 1024; off <<= 1) {
        int add = (t >= off) ? s[t - off] : 0;
        __syncthreads();
        s[t] += add;
        __syncthreads();
    }
    if (t < SCAN_NB) bsum[t] = s[t] - v;
}

__global__ void scan3_kernel(int* __restrict__ out, const int* __restrict__ bsum) {
    int i = blockIdx.x * SCAN_BS + threadIdx.x;
    if (i < HIST_L) out[i] += bsum[blockIdx.x];
    if (i == 0) out[HIST_L] = TOTAL_E;
}

// ---------------------------------------------------------------------------
// Scatter packed entries into bucket-binned arrays.
// dst entry (u32) = src | dl<<17 | rel<<24  -> binned
// src entry (u8)  = sl | rel<<7             -> binnedS (for out-degree counts)
// ---------------------------------------------------------------------------
__global__ __launch_bounds__(512) void scatterA_kernel(const int* __restrict__ s0,
                                                       const int* __restrict__ d0,
                                                       const int* __restrict__ s1,
                                                       const int* __restrict__ d1,
                                                       const int* __restrict__ ofs,
                                                       const int* __restrict__ ofsS,
                                                       unsigned* __restrict__ binned,
                                                       unsigned char* __restrict__ binnedS) {
    __shared__ int cur[NBUCK];
    __shared__ int curS[NBUCK];
    int t = threadIdx.x, wg = blockIdx.x;
    for (int b = t; b < NBUCK; b += 512) {
        cur[b] = ofs[b * NCHUNK + wg];
        curS[b] = ofsS[b * NCHUNK + wg];
    }
    __syncthreads();
    int base = wg * CHUNK;
    for (int i = t; i < CHUNK; i += 512) {
        int e = base + i;
        int rel = (e >= N_EDGES);
        int src = rel ? s1[e - N_EDGES] : s0[e];
        int dst = rel ? d1[e - N_EDGES] : d0[e];
        int p = atomicAdd(&cur[dst >> BSH], 1);
        binned[p] = (unsigned)src | ((unsigned)(dst & 127) << 17) | ((unsigned)rel << 24);
        int q = atomicAdd(&curS[src >> BSH], 1);
        binnedS[q] = (unsigned char)((src & 127) | (rel << 7));
    }
}

// ---------------------------------------------------------------------------
// Per-bucket LDS counting sort (in place): binned -> src indices grouped by
// key = rel<<10 | dl<<3 | src_super (src_super = src>>14, 0..6).
// The src_super minor key makes each (node,rel) segment src-ascending, so
// concurrent gather groups in aggC sweep the src table together (temporal
// locality -> higher L2 hit rate on the 25.6 MB gather tables).
// ---------------------------------------------------------------------------
__global__ __launch_bounds__(512) void sortB_kernel(unsigned* __restrict__ binned,
                                                    const int* __restrict__ ofs,
                                                    int* __restrict__ ip0,
                                                    int* __restrict__ ip1,
                                                    unsigned short* __restrict__ c0a,
                                                    unsigned short* __restrict__ c1a) {
    __shared__ unsigned ent[ENT_CAP];
    __shared__ int cnt[NKEY], pfx[NKEY], cur[NKEY];
    __shared__ int tsum[512];
    int t = threadIdx.x;
    int b = blockIdx.x;
    int start = ofs[b * NCHUNK];
    int end = ofs[(b + 1) * NCHUNK];
    int n = end - start;

    for (int i = t; i < NKEY; i += 512) cnt[i] = 0;
    __syncthreads();
    for (int i = t; i < n; i += 512) {
        unsigned u = binned[start + i];
        if (i < ENT_CAP) ent[i] = u;
        int key = ((int)((u >> 17) & 255) << 3) | (int)((u & 0x1FFFFu) >> 14);
        atomicAdd(&cnt[key], 1);
    }
    __syncthreads();
    // Exclusive scan over NKEY=2048: 4 keys/thread + 512-wide Hillis-Steele.
    int b4 = t * 4;
    int k0 = cnt[b4], k1 = cnt[b4 + 1], k2 = cnt[b4 + 2], k3 = cnt[b4 + 3];
    int s1 = k0 + k1, s2 = s1 + k2, s3 = s2 + k3;
    tsum[t] = s3;
    __syncthreads();
    for (int off = 1; off < 512; off <<= 1) {
        int add = (t >= off) ? tsum[t - off] : 0;
        __syncthreads();
        tsum[t] += add;
        __syncthreads();
    }
    int ex = tsum[t] - s3;
    pfx[b4] = ex;
    pfx[b4 + 1] = ex + k0;
    pfx[b4 + 2] = ex + s1;
    pfx[b4 + 3] = ex + s2;
    cur[b4] = ex;
    cur[b4 + 1] = ex + k0;
    cur[b4 + 2] = ex + s1;
    cur[b4 + 3] = ex + s2;
    __syncthreads();
    for (int i = t; i < n; i += 512) {
        if (i < ENT_CAP) {
            unsigned u = ent[i];
            int key = ((int)((u >> 17) & 255) << 3) | (int)((u & 0x1FFFFu) >> 14);
            int p = atomicAdd(&cur[key], 1);
            binned[start + p] = u & 0x1FFFF;
        }
    }
    if (t < 128) {
        int node = b * 128 + t;
        if (node < N_NODES) {
            int kr0 = t << 3;              // rel0, super0
            int kr1 = (1 << 10) | (t << 3);
            int p0 = pfx[kr0];
            int e0 = pfx[kr0 + 8];         // t=127 -> pfx[1024] = rel1 start. OK.
            int p1 = pfx[kr1];
            int e1 = (t == 127) ? n : pfx[kr1 + 8];
            ip0[node] = start + p0;
            ip1[node] = start + p1;
            c0a[node] = (unsigned short)(e0 - p0);
            c1a[node] = (unsigned short)(e1 - p1);
        }
    }
}

// ---------------------------------------------------------------------------
// Per-src-bucket out-degree counts from the byte-binned entries.
// ---------------------------------------------------------------------------
__global__ __launch_bounds__(512) void countO_kernel(const unsigned char* __restrict__ binnedS,
                                                     const int* __restrict__ ofsS,
                                                     int* __restrict__ cntO0,
                                                     int* __restrict__ cntO1) {
    __shared__ int cnt[256];
    int t = threadIdx.x;
    int b = blockIdx.x;
    int start = ofsS[b * NCHUNK];
    int end = ofsS[(b + 1) * NCHUNK];
    if (t < 256) cnt[t] = 0;
    __syncthreads();
    for (int i = start + t; i < end; i += 512)
        atomicAdd(&cnt[(int)binnedS[i]], 1);
    __syncthreads();
    if (t < 128) {
        int node = b * 128 + t;
        if (node < N_NODES) {
            cntO0[node] = cnt[t];
            cntO1[node] = cnt[t | 128];
        }
    }
}

// ---------------------------------------------------------------------------
// Pre-split W into bf16 hi/lo MFMA B-fragments, per-lane contiguous order:
// Wf[rel][hl][kstep][g][col][j], element (k = kstep*32 + g*8 + j, col).
// ---------------------------------------------------------------------------
__global__ void wprep_kernel(const float* __restrict__ W0,
                             const float* __restrict__ W1,
                             short* __restrict__ Wf) {
    int t = blockIdx.x * blockDim.x + threadIdx.x;
    if (t >= 2 * 4096) return;
    int rel = t >> 12;
    int e = t & 4095;
    int k = e >> 6, col = e & 63;
    float wv = (rel ? W1 : W0)[e];
    unsigned short hi = f32_bf16_rne(wv);
    unsigned short lo = f32_bf16_rne(wv - bf16_f32(hi));
    int kstep = k >> 5, g = (k >> 3) & 3, j = k & 7;
    int base = ((((rel * 2 + 0) * 2 + kstep) * 4 + g) * 64 + col) * 8 + j;
    int baseL = ((((rel * 2 + 1) * 2 + kstep) * 4 + g) * 64 + col) * 8 + j;
    Wf[base] = (short)hi;
    Wf[baseL] = (short)lo;
}

// ---------------------------------------------------------------------------
// MFMA linears: Y0 = (X@W0)*rsqrt(degO0), Y1 = (X@W1)*rsqrt(degO1), fp16 out.
// Split-bf16 (hi+lo, 3 MFMAs). 128 rows/block, 4 waves, 2 m-tiles/wave.
// ---------------------------------------------------------------------------
__global__ __launch_bounds__(256) void lin2m_kernel(const float* __restrict__ x,
                                                    const short* __restrict__ Wf,
                                                    const int* __restrict__ cntO0,
                                                    const int* __restrict__ cntO1,
                                                    __half* __restrict__ y0,
                                                    __half* __restrict__ y1) {
    int t = threadIdx.x;
    int w = t >> 6, lane = t & 63;
    int lr = lane & 15, g = lane >> 4;
    int rowbase = blockIdx.x * 128 + w * 32;

    bf16x8 ah[2][2], al[2][2];
#pragma unroll
    for (int m = 0; m < 2; ++m) {
        int row = rowbase + m * 16 + lr;
        bool ok = row < N_NODES;
        const float* xp = x + (size_t)row * 64 + g * 8;
#pragma unroll
        for (int s = 0; s < 2; ++s) {
            float fv[8];
            if (ok) {
                float4 f0 = ((const float4*)(xp + s * 32))[0];
                float4 f1 = ((const float4*)(xp + s * 32))[1];
                fv[0] = f0.x; fv[1] = f0.y; fv[2] = f0.z; fv[3] = f0.w;
                fv[4] = f1.x; fv[5] = f1.y; fv[6] = f1.z; fv[7] = f1.w;
            } else {
#pragma unroll
                for (int j = 0; j < 8; ++j) fv[j] = 0.f;
            }
#pragma unroll
            for (int j = 0; j < 8; ++j) {
                unsigned short hi = f32_bf16_rne(fv[j]);
                unsigned short lo = f32_bf16_rne(fv[j] - bf16_f32(hi));
                ah[m][s][j] = (short)hi;
                al[m][s][j] = (short)lo;
            }
        }
    }

    float rsc[2][2][4];
#pragma unroll
    for (int m = 0; m < 2; ++m)
#pragma unroll
        for (int reg = 0; reg < 4; ++reg) {
            int row = rowbase + m * 16 + g * 4 + reg;
            bool ok = row < N_NODES;
            rsc[0][m][reg] = ok ? rsqrtf((float)max(cntO0[row], 1)) : 1.f;
            rsc[1][m][reg] = ok ? rsqrtf((float)max(cntO1[row], 1)) : 1.f;
        }

#pragma unroll
    for (int rel = 0; rel < 2; ++rel) {
        __half* yo = rel ? y1 : y0;
        const short* wr = Wf + rel * 8192 + g * 512;
#pragma unroll
        for (int n = 0; n < 4; ++n) {
            const short* wb = wr + (n * 16 + lr) * 8;
            bf16x8 wh0 = *(const bf16x8*)(wb);          // hl=0, kstep=0
            bf16x8 wh1 = *(const bf16x8*)(wb + 2048);   // hl=0, kstep=1
            bf16x8 wl0 = *(const bf16x8*)(wb + 4096);   // hl=1, kstep=0
            bf16x8 wl1 = *(const bf16x8*)(wb + 6144);   // hl=1, kstep=1
#pragma unroll
            for (int m = 0; m < 2; ++m) {
                f32x4 acc = {0.f, 0.f, 0.f, 0.f};
                acc = __builtin_amdgcn_mfma_f32_16x16x32_bf16(al[m][0], wh0, acc, 0, 0, 0);
                acc = __builtin_amdgcn_mfma_f32_16x16x32_bf16(ah[m][0], wl0, acc, 0, 0, 0);
                acc = __builtin_amdgcn_mfma_f32_16x16x32_bf16(ah[m][0], wh0, acc, 0, 0, 0);
                acc = __builtin_amdgcn_mfma_f32_16x16x32_bf16(al[m][1], wh1, acc, 0, 0, 0);
                acc = __builtin_amdgcn_mfma_f32_16x16x32_bf16(ah[m][1], wl1, acc, 0, 0, 0);
                acc = __builtin_amdgcn_mfma_f32_16x16x32_bf16(ah[m][1], wh1, acc, 0, 0, 0);
#pragma unroll
                for (int reg = 0; reg < 4; ++reg) {
                    int row = rowbase + m * 16 + g * 4 + reg;
                    if (row < N_NODES)
                        yo[(size_t)row * 64 + n * 16 + lr] =
                            __float2half_rn(acc[reg] * rsc[rel][m][reg]);
                }
            }
        }
    }
}

// ---------------------------------------------------------------------------
// Gather-aggregate (fp16 rows): one 8-LANE GROUP per dst node. Each lane
// owns 8 dims (16 B per gather). Segments are src-sorted (sortB), so all
// concurrent groups sweep the gather table together -> L2 temporal locality.
// No cross-lane reduction, no idle groups at the store.
// OUTH=0 -> f32 out (layer-1 h); OUTH=1 -> fp16 out (h2).
// ---------------------------------------------------------------------------
template <int RELU, int OUTH>
__global__ __launch_bounds__(256) void aggC_kernel(const __half* __restrict__ L0,
                                                   const __half* __restrict__ L1,
                                                   const unsigned* __restrict__ es,
                                                   const int* __restrict__ ip0,
                                                   const int* __restrict__ ip1,
                                                   const unsigned short* __restrict__ c0a,
                                                   const unsigned short* __restrict__ c1a,
                                                   const float* __restrict__ bia0,
                                                   const float* __restrict__ bia1,
                                                   float* __restrict__ outf,
                                                   __half* __restrict__ outh) {
    int t = threadIdx.x;
    int g = t >> 3, l8 = t & 7;
    int node = blockIdx.x * 32 + g;
    if (node >= N_NODES) return;

    int st0 = ip0[node], c0 = c0a[node];
    int st1 = ip1[node], c1 = c1a[node];

    float a[8] = {0, 0, 0, 0, 0, 0, 0, 0};
    float b[8] = {0, 0, 0, 0, 0, 0, 0, 0};
    union HU { uint4 u; __half2 h[4]; };

    for (int k = 0; k < c0; ++k) {
        int s = (int)es[st0 + k];
        HU uu;
        uu.u = ((const uint4*)(L0 + (size_t)s * 64))[l8];
#pragma unroll
        for (int q = 0; q < 4; ++q) {
            float2 f = __half22float2(uu.h[q]);
            a[2 * q] += f.x;
            a[2 * q + 1] += f.y;
        }
    }
    for (int k = 0; k < c1; ++k) {
        int s = (int)es[st1 + k];
        HU uu;
        uu.u = ((const uint4*)(L1 + (size_t)s * 64))[l8];
#pragma unroll
        for (int q = 0; q < 4; ++q) {
            float2 f = __half22float2(uu.h[q]);
            b[2 * q] += f.x;
            b[2 * q + 1] += f.y;
        }
    }

    float r0 = rsqrtf((float)max(c0, 1));
    float r1 = rsqrtf((float)max(c1, 1));
    float4 u0a = ((const float4*)bia0)[l8 * 2];
    float4 u0b = ((const float4*)bia0)[l8 * 2 + 1];
    float4 u1a = ((const float4*)bia1)[l8 * 2];
    float4 u1b = ((const float4*)bia1)[l8 * 2 + 1];
    float o[8];
#pragma unroll
    for (int q = 0; q < 8; ++q) o[q] = a[q] * r0 + b[q] * r1;
    o[0] += u0a.x + u1a.x; o[1] += u0a.y + u1a.y;
    o[2] += u0a.z + u1a.z; o[3] += u0a.w + u1a.w;
    o[4] += u0b.x + u1b.x; o[5] += u0b.y + u1b.y;
    o[6] += u0b.z + u1b.z; o[7] += u0b.w + u1b.w;
    if (RELU) {
#pragma unroll
        for (int q = 0; q < 8; ++q) o[q] = fmaxf(o[q], 0.f);
    }
    if (OUTH) {
        HU vv;
#pragma unroll
        for (int q = 0; q < 4; ++q)
            vv.h[q] = __floats2half2_rn(o[2 * q], o[2 * q + 1]);
        ((uint4*)(outh + (size_t)node * 64))[l8] = vv.u;
    } else {
        float4 f0 = {o[0], o[1], o[2], o[3]};
        float4 f1 = {o[4], o[5], o[6], o[7]};
        ((float4*)(outf + (size_t)node * 64))[l8 * 2] = f0;
        ((float4*)(outf + (size_t)node * 64))[l8 * 2 + 1] = f1;
    }
}

// ---------------------------------------------------------------------------
// Edge dot products on fp16 h2: 8 threads/edge, 16 B loads, f32 accumulate.
// ---------------------------------------------------------------------------
__global__ __launch_bounds__(256) void score_kernel(const __half* __restrict__ h2,
                                                    const int* __restrict__ ps,
                                                    const int* __restrict__ pd,
                                                    const int* __restrict__ ns,
                                                    const int* __restrict__ nd,
                                                    float* __restrict__ out) {
    int gid = blockIdx.x * blockDim.x + threadIdx.x;
    int e = gid >> 3;
    int l8 = gid & 7;
    if (e >= 2 * N_EDGES) return;
    int s, d;
    if (e < N_EDGES) { s = ps[e]; d = pd[e]; }
    else             { s = ns[e - N_EDGES]; d = nd[e - N_EDGES]; }
    union HU { uint4 u; __half2 h[4]; };
    HU ua, ub;
    ua.u = ((const uint4*)(h2 + (size_t)s * 64))[l8];
    ub.u = ((const uint4*)(h2 + (size_t)d * 64))[l8];
    float p = 0.f;
#pragma unroll
    for (int q = 0; q < 4; ++q) {
        float2 fa = __half22float2(ua.h[q]);
        float2 fb = __half22float2(ub.h[q]);
        p += fa.x * fb.x + fa.y * fb.y;
    }
    p += __shfl_xor(p, 1);
    p += __shfl_xor(p, 2);
    p += __shfl_xor(p, 4);
    if (l8 == 0) out[e] = p;
}

extern "C" void kernel_launch(void* const* d_in, const int* in_sizes, int n_in,
                              void* d_out, int out_size, void* d_ws, size_t ws_size,
                              hipStream_t stream) {
    const float* x    = (const float*)d_in[0];
    const int* s0     = (const int*)d_in[1];
    const int* d0     = (const int*)d_in[2];
    const int* s1     = (const int*)d_in[3];
    const int* d1     = (const int*)d_in[4];
    const int* nsrc   = (const int*)d_in[5];
    const int* ndst   = (const int*)d_in[6];
    const float* W1_0 = (const float*)d_in[7];
    const float* W1_1 = (const float*)d_in[8];
    const float* W2_0 = (const float*)d_in[9];
    const float* W2_1 = (const float*)d_in[10];
    const float* b1_0 = (const float*)d_in[11];
    const float* b1_1 = (const float*)d_in[12];
    const float* b2_0 = (const float*)d_in[13];
    const float* b2_1 = (const float*)d_in[14];
    float* out = (float*)d_out;

    // ---- workspace ----
    char* p = (char*)d_ws;
    int* cntO0 = (int*)p;      p += N_NODES * 4;
    int* cntO1 = (int*)p;      p += N_NODES * 4;
    int* hist  = (int*)p;      p += 2 * HIST_L * 4;          // dst half + src half
    int* ofs   = (int*)p;      p += (HIST_L + 1) * 4;
    int* ofsS  = (int*)p;      p += (HIST_L + 1) * 4;
    int* bsum  = (int*)p;      p += 1024 * 4;
    unsigned* binned = (unsigned*)p;  p += (size_t)TOTAL_E * 4;
    int* ip0   = (int*)p;      p += N_NODES * 4;
    int* ip1   = (int*)p;      p += N_NODES * 4;
    unsigned short* c0a = (unsigned short*)p;  p += N_NODES * 2;
    unsigned short* c1a = (unsigned short*)p;  p += N_NODES * 2;
    unsigned char* binnedS = (unsigned char*)p;  p += (size_t)TOTAL_E;
    p = (char*)(((size_t)p + 255) & ~(size_t)255);
    short* WfA = (short*)p;    p += 16384 * 2;               // layer-1 W frags
    short* WfB = (short*)p;    p += 16384 * 2;               // layer-2 W frags
    p = (char*)(((size_t)p + 255) & ~(size_t)255);
    __half* bufL0h = (__half*)p;  p += (size_t)N_NODES * D * 2;
    __half* bufL1h = (__half*)p;  p += (size_t)N_NODES * D * 2;
    __half* h2h    = (__half*)p;  p += (size_t)N_NODES * D * 2;
    p = (char*)(((size_t)p + 255) & ~(size_t)255);
    float* bufH = (float*)p;   p += (size_t)N_NODES * D * 4;

    const int aggGrid  = (N_NODES + 31) / 32;
    const int scorGrid = (2 * N_EDGES * 8) / 256;

    // ---- W fragment prep (tiny) ----
    wprep_kernel<<<32, 256, 0, stream>>>(W1_0, W1_1, WfA);
    wprep_kernel<<<32, 256, 0, stream>>>(W2_0, W2_1, WfB);

    // ---- degrees + binning (no per-edge global atomics anywhere) ----
    countA_kernel<<<NCHUNK, 512, 0, stream>>>(s0, d0, s1, d1, hist);
    scan1_kernel<<<SCAN_NB, SCAN_BS, 0, stream>>>(hist, ofs, bsum);
    scan2_kernel<<<1, 1024, 0, stream>>>(bsum);
    scan3_kernel<<<SCAN_NB, SCAN_BS, 0, stream>>>(ofs, bsum);
    scan1_kernel<<<SCAN_NB, SCAN_BS, 0, stream>>>(hist + HIST_L, ofsS, bsum);
    scan2_kernel<<<1, 1024, 0, stream>>>(bsum);
    scan3_kernel<<<SCAN_NB, SCAN_BS, 0, stream>>>(ofsS, bsum);
    scatterA_kernel<<<NCHUNK, 512, 0, stream>>>(s0, d0, s1, d1, ofs, ofsS, binned, binnedS);
    sortB_kernel<<<NBUCK, 512, 0, stream>>>(binned, ofs, ip0, ip1, c0a, c1a);
    countO_kernel<<<NBUCK, 512, 0, stream>>>(binnedS, ofsS, cntO0, cntO1);

    // ---- layer 1 ----
    lin2m_kernel<<<L2M_GRID, 256, 0, stream>>>(x, WfA, cntO0, cntO1, bufL0h, bufL1h);
    aggC_kernel<1, 0><<<aggGrid, 256, 0, stream>>>(bufL0h, bufL1h, binned, ip0, ip1,
                                                   c0a, c1a, b1_0, b1_1, bufH, nullptr);

    // ---- layer 2 ----
    lin2m_kernel<<<L2M_GRID, 256, 0, stream>>>(bufH, WfB, cntO0, cntO1, bufL0h, bufL1h);
    aggC_kernel<0, 1><<<aggGrid, 256, 0, stream>>>(bufL0h, bufL1h, binned, ip0, ip1,
                                                   c0a, c1a, b2_0, b2_1, nullptr, h2h);

    // ---- scores ----
    score_kernel<<<scorGrid, 256, 0, stream>>>(h2h, s0, d0, nsrc, ndst, out);
}